// Round 1
// baseline (677.540 us; speedup 1.0000x reference)
//
#include <hip/hip_runtime.h>

// Problem constants (from reference):
//   codes:    (B=64, N=4096, D=64) fp32  -> M = 262144 queries
//   codebook: (NUM_NT=1024, D=64) fp32, rows L2-normalized
// Outputs (concatenated flat in d_out, fp32):
//   quant_codes: M*64 floats, then quant_id: M floats (ids stored as float)

#define NUM_NT 1024
#define DIM 64
#define M_TOTAL (64 * 4096)

// ---------------------------------------------------------------------------
// Pre-kernel: half_csq[k] = 0.5 * sum_d codebook[k][d]^2   (into d_ws)
// ---------------------------------------------------------------------------
__global__ __launch_bounds__(64) void csq_kernel(const float* __restrict__ cb,
                                                 float* __restrict__ half_csq) {
    int k = blockIdx.x;          // one wave per codebook row
    int d = threadIdx.x;         // 64 lanes = 64 dims
    float v = cb[k * DIM + d];
    float s = v * v;
    // full-wave (64-lane) reduction
    #pragma unroll
    for (int off = 32; off > 0; off >>= 1) s += __shfl_down(s, off);
    if (d == 0) half_csq[k] = 0.5f * s;
}

// ---------------------------------------------------------------------------
// Main kernel: one thread per query.
//   score_k = 0.5*||c_k||^2 - x . c_k       (argmin == argmin of dist2)
// Codebook + half_csq are indexed ONLY by wave-uniform k -> scalar loads,
// keeping the VALU pipe 100% on v_fmac_f32.
// ---------------------------------------------------------------------------
__global__ __launch_bounds__(256) void vq_kernel(const float* __restrict__ codes,
                                                 const float* __restrict__ cb,
                                                 const float* __restrict__ half_csq,
                                                 float* __restrict__ out_codes,
                                                 float* __restrict__ out_ids) {
    const int q = blockIdx.x * 256 + threadIdx.x;

    // Load this thread's query vector into registers (16 x float4 = 64 VGPRs).
    const float4* __restrict__ xp =
        reinterpret_cast<const float4*>(codes + (size_t)q * DIM);
    float4 xv[16];
    #pragma unroll
    for (int i = 0; i < 16; ++i) xv[i] = xp[i];

    float best = 3.4e38f;
    int bid = 0;

    for (int k = 0; k < NUM_NT; ++k) {
        const float4* __restrict__ cp =
            reinterpret_cast<const float4*>(cb + k * DIM);
        float acc = half_csq[k];  // scalar load (uniform)
        #pragma unroll
        for (int i = 0; i < 16; ++i) {
            float4 c = cp[i];     // scalar loads (uniform) -> s_load_dwordx*
            acc = fmaf(-xv[i].x, c.x, acc);
            acc = fmaf(-xv[i].y, c.y, acc);
            acc = fmaf(-xv[i].z, c.z, acc);
            acc = fmaf(-xv[i].w, c.w, acc);
        }
        // strict first-min semantics (matches argmin tie-break: lowest index)
        if (acc < best) { best = acc; bid = k; }
    }

    // Gather winning codebook row -> quant_codes (per-lane divergent, L2-hot).
    const float4* __restrict__ bp =
        reinterpret_cast<const float4*>(cb + (size_t)bid * DIM);
    float4* __restrict__ op =
        reinterpret_cast<float4*>(out_codes + (size_t)q * DIM);
    #pragma unroll
    for (int i = 0; i < 16; ++i) op[i] = bp[i];

    out_ids[q] = (float)bid;
}

// ---------------------------------------------------------------------------
extern "C" void kernel_launch(void* const* d_in, const int* in_sizes, int n_in,
                              void* d_out, int out_size, void* d_ws, size_t ws_size,
                              hipStream_t stream) {
    const float* codes = (const float*)d_in[0];   // 16,777,216 fp32
    const float* cb    = (const float*)d_in[1];   // 65,536 fp32
    float* out         = (float*)d_out;

    float* out_codes = out;                              // M*64 floats
    float* out_ids   = out + (size_t)M_TOTAL * DIM;      // M floats
    float* half_csq  = (float*)d_ws;                     // 1024 floats scratch

    csq_kernel<<<NUM_NT, 64, 0, stream>>>(cb, half_csq);
    vq_kernel<<<M_TOTAL / 256, 256, 0, stream>>>(codes, cb, half_csq,
                                                 out_codes, out_ids);
}

// Round 2
// 274.509 us; speedup vs baseline: 2.4682x; 2.4682x over previous
//
#include <hip/hip_runtime.h>

// VQ nearest-neighbor: codes (64,4096,64) fp32, codebook (1024,64) fp32.
// Outputs flat in d_out: quant_codes [M*64] then quant_id [M] (as float).
//
// Strategy: 3-pass bf16 split MFMA GEMM (error <= ~7.5e-4 on score) with
// best/second-best tracking; queries with gap < THR get an exact fp32 rescan.

#define NUM_NT 1024
#define DIM 64
#define M_TOTAL (64 * 4096)
#define NTILES 64              // NUM_NT / 16
#define THR 2.5e-3f            // 3.3x worst-case approx error bound

typedef __attribute__((ext_vector_type(8))) short short8;   // 8 bf16
typedef __attribute__((ext_vector_type(4))) float f32x4;

__device__ __forceinline__ unsigned short f2bf_rne(float f) {
    unsigned u = __builtin_bit_cast(unsigned, f);
    u += 0x7FFFu + ((u >> 16) & 1u);          // round-to-nearest-even
    return (unsigned short)(u >> 16);
}
__device__ __forceinline__ float bf2f(unsigned short h) {
    unsigned u = ((unsigned)h) << 16;
    return __builtin_bit_cast(float, u);
}

// ---------------------------------------------------------------------------
// Phase 0a: hcsq[k] = 0.5 * ||c_k||^2
// ---------------------------------------------------------------------------
__global__ __launch_bounds__(64) void csq_kernel(const float* __restrict__ cb,
                                                 float* __restrict__ hcsq) {
    int k = blockIdx.x, d = threadIdx.x;
    float v = cb[k * DIM + d];
    float s = v * v;
    #pragma unroll
    for (int off = 32; off > 0; off >>= 1) s += __shfl_down(s, off);
    if (d == 0) hcsq[k] = 0.5f * s;
}

// ---------------------------------------------------------------------------
// Phase 0b: codebook -> bf16 hi/lo fragments in MFMA B-layout.
// B frag (16x16x32): col = lane&15, k = 8*(lane>>4)+e. Fragment f = t*2+kk.
// ---------------------------------------------------------------------------
__global__ __launch_bounds__(256) void cb_convert(const float* __restrict__ cb,
                                                  short8* __restrict__ bh,
                                                  short8* __restrict__ bl) {
    int gtid = blockIdx.x * 256 + threadIdx.x;   // 8192 threads = 128 frags x 64
    int f = gtid >> 6;
    int lane = gtid & 63;
    int t = f >> 1, kk = f & 1;
    int n = t * 16 + (lane & 15);
    int k0 = kk * 32 + 8 * (lane >> 4);
    const float* p = cb + n * DIM + k0;
    short8 h, l;
    #pragma unroll
    for (int e = 0; e < 8; ++e) {
        float v = p[e];
        unsigned short hb = f2bf_rne(v);
        h[e] = (short)hb;
        l[e] = (short)f2bf_rne(v - bf2f(hb));
    }
    bh[f * 64 + lane] = h;
    bl[f * 64 + lane] = l;
}

// ---------------------------------------------------------------------------
// Phase 1: approx scores via 3-pass bf16 MFMA + best/second tracking.
// Wave handles 16 query rows x all 1024 codewords.
// A frag: row = lane&15, k = 8*(lane>>4)+e (x negated so MFMA adds -x.c).
// C frag: col = lane&15, row = (lane>>4)*4 + reg.
// out_ids[q]: id (>=0) if safe, -(id+1) if gap < THR (needs exact rescan).
// ---------------------------------------------------------------------------
__global__ __launch_bounds__(256) void vq_approx(const float* __restrict__ codes,
                                                 const short8* __restrict__ bh,
                                                 const short8* __restrict__ bl,
                                                 const float* __restrict__ hcsq,
                                                 float* __restrict__ out_ids) {
    const int lane = threadIdx.x & 63;
    const int wv   = threadIdx.x >> 6;
    const int qb   = (blockIdx.x * 4 + wv) * 16;
    const int c16  = lane & 15;       // A-row / B-col / C-col selector
    const int kg   = lane >> 4;       // k-group

    // Load A (negated query rows), split bf16 hi/lo. 4 frags x 8 bf16.
    const float* xr = codes + (size_t)(qb + c16) * DIM + kg * 8;
    short8 ah0, al0, ah1, al1;
    #pragma unroll
    for (int e = 0; e < 8; ++e) {
        float v = -xr[e];
        unsigned short hb = f2bf_rne(v);
        ah0[e] = (short)hb;
        al0[e] = (short)f2bf_rne(v - bf2f(hb));
        float w = -xr[32 + e];
        unsigned short hw = f2bf_rne(w);
        ah1[e] = (short)hw;
        al1[e] = (short)f2bf_rne(w - bf2f(hw));
    }

    float d1[4], d2[4];
    int   tb[4];
    #pragma unroll
    for (int r = 0; r < 4; ++r) { d1[r] = 3.4e38f; d2[r] = 3.4e38f; tb[r] = 0; }

    #pragma unroll 2
    for (int t = 0; t < NTILES; ++t) {
        short8 vh0 = bh[(t * 2 + 0) * 64 + lane];
        short8 vl0 = bl[(t * 2 + 0) * 64 + lane];
        short8 vh1 = bh[(t * 2 + 1) * 64 + lane];
        short8 vl1 = bl[(t * 2 + 1) * 64 + lane];
        float ch = hcsq[t * 16 + c16];
        f32x4 acc = {ch, ch, ch, ch};   // score = 0.5*||c||^2 - x.c
        acc = __builtin_amdgcn_mfma_f32_16x16x32_bf16(ah0, vh0, acc, 0, 0, 0);
        acc = __builtin_amdgcn_mfma_f32_16x16x32_bf16(al0, vh0, acc, 0, 0, 0);
        acc = __builtin_amdgcn_mfma_f32_16x16x32_bf16(ah0, vl0, acc, 0, 0, 0);
        acc = __builtin_amdgcn_mfma_f32_16x16x32_bf16(ah1, vh1, acc, 0, 0, 0);
        acc = __builtin_amdgcn_mfma_f32_16x16x32_bf16(al1, vh1, acc, 0, 0, 0);
        acc = __builtin_amdgcn_mfma_f32_16x16x32_bf16(ah1, vl1, acc, 0, 0, 0);
        #pragma unroll
        for (int r = 0; r < 4; ++r) {
            float d = acc[r];
            bool take = d < d1[r];                    // strict: first min wins
            d2[r] = fminf(d2[r], fmaxf(d1[r], d));    // running second-best
            d1[r] = fminf(d1[r], d);
            tb[r] = take ? t : tb[r];
        }
    }

    // Cross-lane argmin within each 16-lane group (same kg = same 4 rows).
    #pragma unroll
    for (int r = 0; r < 4; ++r) {
        float dd1 = d1[r], dd2 = d2[r];
        int idv = tb[r] * 16 + c16;
        #pragma unroll
        for (int m = 1; m < 16; m <<= 1) {
            float d_o  = __shfl_xor(dd1, m, 64);
            int   i_o  = __shfl_xor(idv, m, 64);
            float d2_o = __shfl_xor(dd2, m, 64);
            float nd2 = fminf(fminf(dd2, d2_o), fmaxf(dd1, d_o));
            bool take = (d_o < dd1) || (d_o == dd1 && i_o < idv);
            dd1 = take ? d_o : dd1;
            idv = take ? i_o : idv;
            dd2 = nd2;
        }
        if (c16 == 0) {
            int q = qb + kg * 4 + r;
            out_ids[q] = (dd2 - dd1 < THR) ? -(float)(idv + 1) : (float)idv;
        }
    }
}

// ---------------------------------------------------------------------------
// Phase 2: one wave per query. Flagged queries -> exact fp32 rescan (same FMA
// order as round-1 kernel which matched numpy exactly). All queries: gather
// codebook row + write id.
// ---------------------------------------------------------------------------
__global__ __launch_bounds__(256) void vq_finalize(const float* __restrict__ codes,
                                                   const float* __restrict__ cb,
                                                   const float* __restrict__ hcsq,
                                                   float* __restrict__ out_codes,
                                                   float* __restrict__ out_ids) {
    const int lane = threadIdx.x & 63;
    const int q = blockIdx.x * 4 + (threadIdx.x >> 6);
    float fid = out_ids[q];
    int id;
    if (fid >= 0.0f) {
        id = (int)fid;
    } else {
        // exact rescan: lane handles k = lane + 64*j
        float x[64];
        const float4* xp = reinterpret_cast<const float4*>(codes + (size_t)q * DIM);
        #pragma unroll
        for (int i = 0; i < 16; ++i) {
            float4 v = xp[i];
            x[4*i+0] = v.x; x[4*i+1] = v.y; x[4*i+2] = v.z; x[4*i+3] = v.w;
        }
        float best = 3.4e38f; int bid = 0;
        for (int j = 0; j < 16; ++j) {
            int k = j * 64 + lane;
            const float4* cp = reinterpret_cast<const float4*>(cb + (size_t)k * DIM);
            float acc = hcsq[k];
            #pragma unroll
            for (int i = 0; i < 16; ++i) {
                float4 c = cp[i];
                acc = fmaf(-x[4*i+0], c.x, acc);
                acc = fmaf(-x[4*i+1], c.y, acc);
                acc = fmaf(-x[4*i+2], c.z, acc);
                acc = fmaf(-x[4*i+3], c.w, acc);
            }
            if (acc < best) { best = acc; bid = k; }  // strict: lowest k wins
        }
        #pragma unroll
        for (int m = 1; m < 64; m <<= 1) {
            float d_o = __shfl_xor(best, m, 64);
            int   i_o = __shfl_xor(bid, m, 64);
            bool take = (d_o < best) || (d_o == best && i_o < bid);
            best = take ? d_o : best;
            bid  = take ? i_o : bid;
        }
        id = __shfl(bid, 0, 64);
    }
    // coalesced gather + writes
    out_codes[(size_t)q * DIM + lane] = cb[id * DIM + lane];
    if (lane == 0) out_ids[q] = (float)id;
}

// ---------------------------------------------------------------------------
extern "C" void kernel_launch(void* const* d_in, const int* in_sizes, int n_in,
                              void* d_out, int out_size, void* d_ws, size_t ws_size,
                              hipStream_t stream) {
    const float* codes = (const float*)d_in[0];
    const float* cb    = (const float*)d_in[1];
    float* out         = (float*)d_out;

    float* out_codes = out;
    float* out_ids   = out + (size_t)M_TOTAL * DIM;

    // ws layout: [0,4KB) hcsq | [4KB,132KB) bh | [132KB,260KB) bl
    float*  hcsq = (float*)d_ws;
    short8* bh   = (short8*)((char*)d_ws + 4096);
    short8* bl   = (short8*)((char*)d_ws + 4096 + 128 * 1024);

    csq_kernel<<<NUM_NT, 64, 0, stream>>>(cb, hcsq);
    cb_convert<<<32, 256, 0, stream>>>(cb, bh, bl);
    vq_approx<<<M_TOTAL / 64, 256, 0, stream>>>(codes, bh, bl, hcsq, out_ids);
    vq_finalize<<<M_TOTAL / 4, 256, 0, stream>>>(codes, cb, hcsq, out_codes, out_ids);
}

// Round 5
// 247.603 us; speedup vs baseline: 2.7364x; 1.1087x over previous
//
#include <hip/hip_runtime.h>

// VQ nearest-neighbor: codes (64,4096,64) fp32, codebook (1024,64) fp32.
// Outputs flat in d_out: quant_codes [M*64] f32, then quant_id [M] (as f32).
//
// Round 5 = round 2 (verified pass, 274us) with ONE change: vq_approx does
// 64 queries/wave (4 A-sets share each B-fragment load) to cut L2 traffic
// 4x. Tracking, reduction, marker, and finalize logic are r2-verbatim.

#define NUM_NT 1024
#define DIM 64
#define M_TOTAL (64 * 4096)
#define NTILES 64
#define THR 2.5e-3f            // raw-gap threshold, verified in round 2

typedef __attribute__((ext_vector_type(8))) short short8;   // 8 bf16
typedef __attribute__((ext_vector_type(4))) float f32x4;

static __device__ __forceinline__ unsigned short f2bf_rne(float f) {
    unsigned u = __builtin_bit_cast(unsigned, f);
    u += 0x7FFFu + ((u >> 16) & 1u);          // round-to-nearest-even
    return (unsigned short)(u >> 16);
}
static __device__ __forceinline__ float bf2f(unsigned short h) {
    unsigned u = ((unsigned)h) << 16;
    return __builtin_bit_cast(float, u);
}

// ---------------------------------------------------------------------------
// Phase 0a: hcsq[k] = 0.5 * ||c_k||^2   (r2-verbatim)
// ---------------------------------------------------------------------------
__global__ __launch_bounds__(64) void csq_kernel(const float* __restrict__ cb,
                                                 float* __restrict__ hcsq) {
    int k = blockIdx.x, d = threadIdx.x;
    float v = cb[k * DIM + d];
    float s = v * v;
    #pragma unroll
    for (int off = 32; off > 0; off >>= 1) s += __shfl_down(s, off);
    if (d == 0) hcsq[k] = 0.5f * s;
}

// ---------------------------------------------------------------------------
// Phase 0b: codebook -> bf16 hi/lo fragments in MFMA B-layout (r2-verbatim).
// B frag (16x16x32): col = lane&15, k = 8*(lane>>4)+e. Fragment f = t*2+kk.
// ---------------------------------------------------------------------------
__global__ __launch_bounds__(256) void cb_convert(const float* __restrict__ cb,
                                                  short8* __restrict__ bh,
                                                  short8* __restrict__ bl) {
    int gtid = blockIdx.x * 256 + threadIdx.x;   // 8192 = 128 frags x 64 lanes
    int f = gtid >> 6;
    int lane = gtid & 63;
    int t = f >> 1, kk = f & 1;
    int n = t * 16 + (lane & 15);
    int k0 = kk * 32 + 8 * (lane >> 4);
    const float* p = cb + n * DIM + k0;
    short8 h, l;
    #pragma unroll
    for (int e = 0; e < 8; ++e) {
        float v = p[e];
        unsigned short hb = f2bf_rne(v);
        h[e] = (short)hb;
        l[e] = (short)f2bf_rne(v - bf2f(hb));
    }
    bh[f * 64 + lane] = h;
    bl[f * 64 + lane] = l;
}

// ---------------------------------------------------------------------------
// Phase 1: approx scores via 3-pass bf16 MFMA, 64 queries per wave.
// Per A-set s (16 queries), tracking/update/reduction is r2-VERBATIM:
//   d1/d2 float best/second, tb tile index, strict-< first-min,
//   lexicographic (score, id) 16-lane butterfly.
// out_ids[q]: id if gap >= THR, -(id+1) if flagged for exact rescan.
// ---------------------------------------------------------------------------
__global__ __launch_bounds__(256) void vq_approx(const float* __restrict__ codes,
                                                 const short8* __restrict__ bh,
                                                 const short8* __restrict__ bl,
                                                 const float* __restrict__ hcsq,
                                                 float* __restrict__ out_ids) {
    const int lane = threadIdx.x & 63;
    const int wv   = threadIdx.x >> 6;
    const int qb   = (blockIdx.x * 4 + wv) * 64;   // 64 queries per wave
    const int c16  = lane & 15;
    const int kg   = lane >> 4;

    // Load + split 4 A-sets (negated query rows), bf16 hi/lo (r2-style
    // scalar element reads).
    short8 ah[4][2], al[4][2];
    #pragma unroll
    for (int s = 0; s < 4; ++s) {
        const float* xr = codes + (size_t)(qb + s * 16 + c16) * DIM + kg * 8;
        #pragma unroll
        for (int e = 0; e < 8; ++e) {
            float v = -xr[e];
            unsigned short hb = f2bf_rne(v);
            ah[s][0][e] = (short)hb;
            al[s][0][e] = (short)f2bf_rne(v - bf2f(hb));
            float w = -xr[32 + e];
            unsigned short hw = f2bf_rne(w);
            ah[s][1][e] = (short)hw;
            al[s][1][e] = (short)f2bf_rne(w - bf2f(hw));
        }
    }

    float d1[16], d2[16];
    int   tb[16];
    #pragma unroll
    for (int r = 0; r < 16; ++r) { d1[r] = 3.4e38f; d2[r] = 3.4e38f; tb[r] = 0; }

    for (int t = 0; t < NTILES; ++t) {
        short8 vh0 = bh[(t * 2 + 0) * 64 + lane];
        short8 vl0 = bl[(t * 2 + 0) * 64 + lane];
        short8 vh1 = bh[(t * 2 + 1) * 64 + lane];
        short8 vl1 = bl[(t * 2 + 1) * 64 + lane];
        float hc = hcsq[t * 16 + c16];
        f32x4 hcv = {hc, hc, hc, hc};
        #pragma unroll
        for (int s = 0; s < 4; ++s) {
            f32x4 acc = hcv;   // score = 0.5*||c||^2 - x.c
            acc = __builtin_amdgcn_mfma_f32_16x16x32_bf16(ah[s][0], vh0, acc, 0, 0, 0);
            acc = __builtin_amdgcn_mfma_f32_16x16x32_bf16(al[s][0], vh0, acc, 0, 0, 0);
            acc = __builtin_amdgcn_mfma_f32_16x16x32_bf16(ah[s][0], vl0, acc, 0, 0, 0);
            acc = __builtin_amdgcn_mfma_f32_16x16x32_bf16(ah[s][1], vh1, acc, 0, 0, 0);
            acc = __builtin_amdgcn_mfma_f32_16x16x32_bf16(al[s][1], vh1, acc, 0, 0, 0);
            acc = __builtin_amdgcn_mfma_f32_16x16x32_bf16(ah[s][1], vl1, acc, 0, 0, 0);
            #pragma unroll
            for (int rr = 0; rr < 4; ++rr) {
                float d = acc[rr];
                int r = s * 4 + rr;
                bool take = d < d1[r];                    // strict: first min wins
                d2[r] = fminf(d2[r], fmaxf(d1[r], d));    // running second-best
                d1[r] = fminf(d1[r], d);
                tb[r] = take ? t : tb[r];
            }
        }
    }

    // Cross-lane argmin within each 16-lane group (r2-verbatim butterfly).
    #pragma unroll
    for (int r = 0; r < 16; ++r) {
        float dd1 = d1[r], dd2 = d2[r];
        int idv = tb[r] * 16 + c16;
        #pragma unroll
        for (int m = 1; m < 16; m <<= 1) {
            float d_o  = __shfl_xor(dd1, m, 64);
            int   i_o  = __shfl_xor(idv, m, 64);
            float d2_o = __shfl_xor(dd2, m, 64);
            float nd2 = fminf(fminf(dd2, d2_o), fmaxf(dd1, d_o));
            bool take = (d_o < dd1) || (d_o == dd1 && i_o < idv);
            dd1 = take ? d_o : dd1;
            idv = take ? i_o : idv;
            dd2 = nd2;
        }
        if (c16 == 0) {
            int q = qb + (r >> 2) * 16 + kg * 4 + (r & 3);
            out_ids[q] = (dd2 - dd1 < THR) ? -(float)(idv + 1) : (float)idv;
        }
    }
}

// ---------------------------------------------------------------------------
// Phase 2 (r2-VERBATIM): one wave per query. Flagged queries -> exact fp32
// rescan (bitwise-identical to validated round-1 math). ALL queries: gather
// codebook row + unconditional id rewrite.
// ---------------------------------------------------------------------------
__global__ __launch_bounds__(256) void vq_finalize(const float* __restrict__ codes,
                                                   const float* __restrict__ cb,
                                                   const float* __restrict__ hcsq,
                                                   float* __restrict__ out_codes,
                                                   float* __restrict__ out_ids) {
    const int lane = threadIdx.x & 63;
    const int q = blockIdx.x * 4 + (threadIdx.x >> 6);
    float fid = out_ids[q];
    int id;
    if (fid >= 0.0f) {
        id = (int)fid;
    } else {
        // exact rescan: lane handles k = lane + 64*j
        float x[64];
        const float4* xp = reinterpret_cast<const float4*>(codes + (size_t)q * DIM);
        #pragma unroll
        for (int i = 0; i < 16; ++i) {
            float4 v = xp[i];
            x[4*i+0] = v.x; x[4*i+1] = v.y; x[4*i+2] = v.z; x[4*i+3] = v.w;
        }
        float best = 3.4e38f; int bid = 0;
        for (int j = 0; j < 16; ++j) {
            int k = j * 64 + lane;
            const float4* cp = reinterpret_cast<const float4*>(cb + (size_t)k * DIM);
            float acc = hcsq[k];
            #pragma unroll
            for (int i = 0; i < 16; ++i) {
                float4 c = cp[i];
                acc = fmaf(-x[4*i+0], c.x, acc);
                acc = fmaf(-x[4*i+1], c.y, acc);
                acc = fmaf(-x[4*i+2], c.z, acc);
                acc = fmaf(-x[4*i+3], c.w, acc);
            }
            if (acc < best) { best = acc; bid = k; }  // strict: lowest k wins
        }
        #pragma unroll
        for (int m = 1; m < 64; m <<= 1) {
            float d_o = __shfl_xor(best, m, 64);
            int   i_o = __shfl_xor(bid, m, 64);
            bool take = (d_o < best) || (d_o == best && i_o < bid);
            best = take ? d_o : best;
            bid  = take ? i_o : bid;
        }
        id = __shfl(bid, 0, 64);
    }
    // coalesced gather + writes
    out_codes[(size_t)q * DIM + lane] = cb[id * DIM + lane];
    if (lane == 0) out_ids[q] = (float)id;
}

// ---------------------------------------------------------------------------
extern "C" void kernel_launch(void* const* d_in, const int* in_sizes, int n_in,
                              void* d_out, int out_size, void* d_ws, size_t ws_size,
                              hipStream_t stream) {
    const float* codes = (const float*)d_in[0];
    const float* cb    = (const float*)d_in[1];
    float* out         = (float*)d_out;

    float* out_codes = out;
    float* out_ids   = out + (size_t)M_TOTAL * DIM;

    // ws: [0,4KB) hcsq | [4KB,132KB) bh | [132KB,260KB) bl
    float*  hcsq = (float*)d_ws;
    short8* bh   = (short8*)((char*)d_ws + 4096);
    short8* bl   = (short8*)((char*)d_ws + 4096 + 128 * 1024);

    csq_kernel<<<NUM_NT, 64, 0, stream>>>(cb, hcsq);
    cb_convert<<<32, 256, 0, stream>>>(cb, bh, bl);
    vq_approx<<<M_TOTAL / 256, 256, 0, stream>>>(codes, bh, bl, hcsq, out_ids);
    vq_finalize<<<M_TOTAL / 4, 256, 0, stream>>>(codes, cb, hcsq,
                                                 out_codes, out_ids);
}

// Round 6
// 243.434 us; speedup vs baseline: 2.7833x; 1.0171x over previous
//
#include <hip/hip_runtime.h>

// VQ nearest-neighbor: codes (64,4096,64) fp32, codebook (1024,64) fp32.
// Outputs flat in d_out: quant_codes [M*64] f32, then quant_id [M] (as f32).
//
// Round 6 = round 5 (verified, 247us) with two local changes:
//  (a) vq_approx: register double-buffer prefetch of next tile's B frags +
//      v_med3_f32 for second-best tracking (r5 reduction/marker verbatim).
//  (b) finalize: 4 queries/wave, float4 gather/store (r1-verbatim rescan).

#define NUM_NT 1024
#define DIM 64
#define M_TOTAL (64 * 4096)
#define NTILES 64
#define THR 2.5e-3f            // raw-gap threshold, verified in rounds 2/5

typedef __attribute__((ext_vector_type(8))) short short8;   // 8 bf16
typedef __attribute__((ext_vector_type(4))) float f32x4;

static __device__ __forceinline__ unsigned short f2bf_rne(float f) {
    unsigned u = __builtin_bit_cast(unsigned, f);
    u += 0x7FFFu + ((u >> 16) & 1u);          // round-to-nearest-even
    return (unsigned short)(u >> 16);
}
static __device__ __forceinline__ float bf2f(unsigned short h) {
    unsigned u = ((unsigned)h) << 16;
    return __builtin_bit_cast(float, u);
}

// ---------------------------------------------------------------------------
// Phase 0a: hcsq[k] = 0.5 * ||c_k||^2   (verified)
// ---------------------------------------------------------------------------
__global__ __launch_bounds__(64) void csq_kernel(const float* __restrict__ cb,
                                                 float* __restrict__ hcsq) {
    int k = blockIdx.x, d = threadIdx.x;
    float v = cb[k * DIM + d];
    float s = v * v;
    #pragma unroll
    for (int off = 32; off > 0; off >>= 1) s += __shfl_down(s, off);
    if (d == 0) hcsq[k] = 0.5f * s;
}

// ---------------------------------------------------------------------------
// Phase 0b: codebook -> bf16 hi/lo fragments in MFMA B-layout (verified).
// B frag (16x16x32): col = lane&15, k = 8*(lane>>4)+e. Fragment f = t*2+kk.
// ---------------------------------------------------------------------------
__global__ __launch_bounds__(256) void cb_convert(const float* __restrict__ cb,
                                                  short8* __restrict__ bh,
                                                  short8* __restrict__ bl) {
    int gtid = blockIdx.x * 256 + threadIdx.x;   // 8192 = 128 frags x 64 lanes
    int f = gtid >> 6;
    int lane = gtid & 63;
    int t = f >> 1, kk = f & 1;
    int n = t * 16 + (lane & 15);
    int k0 = kk * 32 + 8 * (lane >> 4);
    const float* p = cb + n * DIM + k0;
    short8 h, l;
    #pragma unroll
    for (int e = 0; e < 8; ++e) {
        float v = p[e];
        unsigned short hb = f2bf_rne(v);
        h[e] = (short)hb;
        l[e] = (short)f2bf_rne(v - bf2f(hb));
    }
    bh[f * 64 + lane] = h;
    bl[f * 64 + lane] = l;
}

// ---------------------------------------------------------------------------
// Phase 1: approx scores via 3-pass bf16 MFMA, 64 queries/wave.
// Changes vs r5: next-tile B prefetch into named registers (no arrays);
// d2 update via fmed3 (min(d2,max(d1,d)) == median(d1,d2,d) when d1<=d2).
// Reduction, marker logic, q-mapping: r5-VERBATIM.
// ---------------------------------------------------------------------------
__global__ __launch_bounds__(256) void vq_approx(const float* __restrict__ codes,
                                                 const short8* __restrict__ bh,
                                                 const short8* __restrict__ bl,
                                                 const float* __restrict__ hcsq,
                                                 float* __restrict__ out_ids) {
    const int lane = threadIdx.x & 63;
    const int wv   = threadIdx.x >> 6;
    const int qb   = (blockIdx.x * 4 + wv) * 64;   // 64 queries per wave
    const int c16  = lane & 15;
    const int kg   = lane >> 4;

    // Load + split 4 A-sets (negated query rows), bf16 hi/lo (r5-verbatim).
    short8 ah[4][2], al[4][2];
    #pragma unroll
    for (int s = 0; s < 4; ++s) {
        const float* xr = codes + (size_t)(qb + s * 16 + c16) * DIM + kg * 8;
        #pragma unroll
        for (int e = 0; e < 8; ++e) {
            float v = -xr[e];
            unsigned short hb = f2bf_rne(v);
            ah[s][0][e] = (short)hb;
            al[s][0][e] = (short)f2bf_rne(v - bf2f(hb));
            float w = -xr[32 + e];
            unsigned short hw = f2bf_rne(w);
            ah[s][1][e] = (short)hw;
            al[s][1][e] = (short)f2bf_rne(w - bf2f(hw));
        }
    }

    float d1[16], d2[16];
    int   tb[16];
    #pragma unroll
    for (int r = 0; r < 16; ++r) { d1[r] = 3.4e38f; d2[r] = 3.4e38f; tb[r] = 0; }

    // Prefetch tile 0 B-fragments.
    short8 pvh0 = bh[0 * 64 + lane];
    short8 pvl0 = bl[0 * 64 + lane];
    short8 pvh1 = bh[1 * 64 + lane];
    short8 pvl1 = bl[1 * 64 + lane];
    float  phc  = hcsq[c16];

    for (int t = 0; t < NTILES; ++t) {
        // rotate: current <- prefetched
        short8 vh0 = pvh0, vl0 = pvl0, vh1 = pvh1, vl1 = pvl1;
        float  hc  = phc;
        if (t + 1 < NTILES) {          // issue next-tile loads before MFMA
            pvh0 = bh[(t * 2 + 2) * 64 + lane];
            pvl0 = bl[(t * 2 + 2) * 64 + lane];
            pvh1 = bh[(t * 2 + 3) * 64 + lane];
            pvl1 = bl[(t * 2 + 3) * 64 + lane];
            phc  = hcsq[(t + 1) * 16 + c16];
        }
        f32x4 hcv = {hc, hc, hc, hc};
        #pragma unroll
        for (int s = 0; s < 4; ++s) {
            f32x4 acc = hcv;   // score = 0.5*||c||^2 - x.c
            acc = __builtin_amdgcn_mfma_f32_16x16x32_bf16(ah[s][0], vh0, acc, 0, 0, 0);
            acc = __builtin_amdgcn_mfma_f32_16x16x32_bf16(al[s][0], vh0, acc, 0, 0, 0);
            acc = __builtin_amdgcn_mfma_f32_16x16x32_bf16(ah[s][0], vl0, acc, 0, 0, 0);
            acc = __builtin_amdgcn_mfma_f32_16x16x32_bf16(ah[s][1], vh1, acc, 0, 0, 0);
            acc = __builtin_amdgcn_mfma_f32_16x16x32_bf16(al[s][1], vh1, acc, 0, 0, 0);
            acc = __builtin_amdgcn_mfma_f32_16x16x32_bf16(ah[s][1], vl1, acc, 0, 0, 0);
            #pragma unroll
            for (int rr = 0; rr < 4; ++rr) {
                float d = acc[rr];
                int r = s * 4 + rr;
                bool take = d < d1[r];                    // strict: first min wins
                d2[r] = __builtin_amdgcn_fmed3f(d1[r], d2[r], d);  // = min(d2,max(d1,d))
                d1[r] = fminf(d1[r], d);
                tb[r] = take ? t : tb[r];
            }
        }
    }

    // Cross-lane argmin within each 16-lane group (r5-verbatim butterfly).
    #pragma unroll
    for (int r = 0; r < 16; ++r) {
        float dd1 = d1[r], dd2 = d2[r];
        int idv = tb[r] * 16 + c16;
        #pragma unroll
        for (int m = 1; m < 16; m <<= 1) {
            float d_o  = __shfl_xor(dd1, m, 64);
            int   i_o  = __shfl_xor(idv, m, 64);
            float d2_o = __shfl_xor(dd2, m, 64);
            float nd2 = fminf(fminf(dd2, d2_o), fmaxf(dd1, d_o));
            bool take = (d_o < dd1) || (d_o == dd1 && i_o < idv);
            dd1 = take ? d_o : dd1;
            idv = take ? i_o : idv;
            dd2 = nd2;
        }
        if (c16 == 0) {
            int q = qb + (r >> 2) * 16 + kg * 4 + (r & 3);
            out_ids[q] = (dd2 - dd1 < THR) ? -(float)(idv + 1) : (float)idv;
        }
    }
}

// ---------------------------------------------------------------------------
// Phase 2: 4 queries per wave. Flagged queries -> exact fp32 whole-wave
// rescan (bitwise-identical to validated round-1 math). All queries:
// float4 gather of winning row + float4 store + id rewrite.
// ---------------------------------------------------------------------------
__global__ __launch_bounds__(256) void vq_finalize4(const float* __restrict__ codes,
                                                    const float* __restrict__ cb,
                                                    const float* __restrict__ hcsq,
                                                    float* __restrict__ out_codes,
                                                    float* __restrict__ out_ids) {
    const int lane = threadIdx.x & 63;
    const int wv   = threadIdx.x >> 6;
    const int qw   = (blockIdx.x * 4 + wv) * 4;   // 4 queries per wave

    float fid = (lane < 4) ? out_ids[qw + lane] : 0.0f;
    int myid = 0;   // lanes 0..3 keep resolved id of query qw+lane

    #pragma unroll
    for (int j = 0; j < 4; ++j) {
        float f = __shfl(fid, j, 64);     // wave-uniform
        int id;
        if (f >= 0.0f) {
            id = (int)f;
        } else {
            // exact rescan of q = qw+j (r1-verbatim math): lane owns k=lane+64*jj
            const int q = qw + j;
            float x[64];
            const float4* xp = reinterpret_cast<const float4*>(codes + (size_t)q * DIM);
            #pragma unroll
            for (int i = 0; i < 16; ++i) {
                float4 v = xp[i];
                x[4*i+0] = v.x; x[4*i+1] = v.y; x[4*i+2] = v.z; x[4*i+3] = v.w;
            }
            float best = 3.4e38f; int bid = 0;
            for (int jj = 0; jj < 16; ++jj) {
                int k = jj * 64 + lane;
                const float4* cp = reinterpret_cast<const float4*>(cb + (size_t)k * DIM);
                float acc = hcsq[k];
                #pragma unroll
                for (int i = 0; i < 16; ++i) {
                    float4 c = cp[i];
                    acc = fmaf(-x[4*i+0], c.x, acc);
                    acc = fmaf(-x[4*i+1], c.y, acc);
                    acc = fmaf(-x[4*i+2], c.z, acc);
                    acc = fmaf(-x[4*i+3], c.w, acc);
                }
                if (acc < best) { best = acc; bid = k; }  // strict: lowest k wins
            }
            #pragma unroll
            for (int m = 1; m < 64; m <<= 1) {
                float d_o = __shfl_xor(best, m, 64);
                int   i_o = __shfl_xor(bid, m, 64);
                bool take = (d_o < best) || (d_o == best && i_o < bid);
                best = take ? d_o : best;
                bid  = take ? i_o : bid;
            }
            id = __shfl(bid, 0, 64);
        }
        if (lane == j) myid = id;
    }

    // Gather + write: 16-lane group per query, float4 per lane.
    const int qi = lane >> 4;                 // which of the 4 queries
    const int gid = __shfl(myid, qi, 64);     // id resolved by lane qi
    const float4* cb4 = reinterpret_cast<const float4*>(cb);
    float4 row = cb4[(size_t)gid * 16 + (lane & 15)];
    reinterpret_cast<float4*>(out_codes)[(size_t)(qw + qi) * 16 + (lane & 15)] = row;
    if (lane < 4) out_ids[qw + lane] = (float)myid;
}

// ---------------------------------------------------------------------------
extern "C" void kernel_launch(void* const* d_in, const int* in_sizes, int n_in,
                              void* d_out, int out_size, void* d_ws, size_t ws_size,
                              hipStream_t stream) {
    const float* codes = (const float*)d_in[0];
    const float* cb    = (const float*)d_in[1];
    float* out         = (float*)d_out;

    float* out_codes = out;
    float* out_ids   = out + (size_t)M_TOTAL * DIM;

    // ws: [0,4KB) hcsq | [4KB,132KB) bh | [132KB,260KB) bl
    float*  hcsq = (float*)d_ws;
    short8* bh   = (short8*)((char*)d_ws + 4096);
    short8* bl   = (short8*)((char*)d_ws + 4096 + 128 * 1024);

    csq_kernel<<<NUM_NT, 64, 0, stream>>>(cb, hcsq);
    cb_convert<<<32, 256, 0, stream>>>(cb, bh, bl);
    vq_approx<<<M_TOTAL / 256, 256, 0, stream>>>(codes, bh, bl, hcsq, out_ids);
    vq_finalize4<<<M_TOTAL / 16, 256, 0, stream>>>(codes, cb, hcsq,
                                                   out_codes, out_ids);
}

// Round 7
// 222.840 us; speedup vs baseline: 3.0405x; 1.0924x over previous
//
#include <hip/hip_runtime.h>

// VQ nearest-neighbor: codes (64,4096,64) fp32, codebook (1024,64) fp32.
// Outputs flat in d_out: quant_codes [M*64] f32, then quant_id [M] (as f32).
//
// Round 7 = round 6's verified vq_approx + split finalize:
//   - approx writes positive ids always; flagged queries pushed to worklist
//   - vq_fixup: rescans ONLY worklist entries (scratch confined here)
//   - vq_gather: scratch-free streaming gather/store of codebook rows

#define NUM_NT 1024
#define DIM 64
#define M_TOTAL (64 * 4096)
#define NTILES 64
#define THR 2.5e-3f            // raw-gap threshold, verified rounds 2/5/6

typedef __attribute__((ext_vector_type(8))) short short8;   // 8 bf16
typedef __attribute__((ext_vector_type(4))) float f32x4;

static __device__ __forceinline__ unsigned short f2bf_rne(float f) {
    unsigned u = __builtin_bit_cast(unsigned, f);
    u += 0x7FFFu + ((u >> 16) & 1u);          // round-to-nearest-even
    return (unsigned short)(u >> 16);
}
static __device__ __forceinline__ float bf2f(unsigned short h) {
    unsigned u = ((unsigned)h) << 16;
    return __builtin_bit_cast(float, u);
}

// ---------------------------------------------------------------------------
// Phase 0a: hcsq[k] = 0.5*||c_k||^2; block 0 also zeroes the worklist counter.
// ---------------------------------------------------------------------------
__global__ __launch_bounds__(64) void csq_kernel(const float* __restrict__ cb,
                                                 float* __restrict__ hcsq,
                                                 int* __restrict__ counter) {
    int k = blockIdx.x, d = threadIdx.x;
    if (k == 0 && d == 0) *counter = 0;
    float v = cb[k * DIM + d];
    float s = v * v;
    #pragma unroll
    for (int off = 32; off > 0; off >>= 1) s += __shfl_down(s, off);
    if (d == 0) hcsq[k] = 0.5f * s;
}

// ---------------------------------------------------------------------------
// Phase 0b: codebook -> bf16 hi/lo fragments in MFMA B-layout (verified).
// ---------------------------------------------------------------------------
__global__ __launch_bounds__(256) void cb_convert(const float* __restrict__ cb,
                                                  short8* __restrict__ bh,
                                                  short8* __restrict__ bl) {
    int gtid = blockIdx.x * 256 + threadIdx.x;   // 8192 = 128 frags x 64 lanes
    int f = gtid >> 6;
    int lane = gtid & 63;
    int t = f >> 1, kk = f & 1;
    int n = t * 16 + (lane & 15);
    int k0 = kk * 32 + 8 * (lane >> 4);
    const float* p = cb + n * DIM + k0;
    short8 h, l;
    #pragma unroll
    for (int e = 0; e < 8; ++e) {
        float v = p[e];
        unsigned short hb = f2bf_rne(v);
        h[e] = (short)hb;
        l[e] = (short)f2bf_rne(v - bf2f(hb));
    }
    bh[f * 64 + lane] = h;
    bl[f * 64 + lane] = l;
}

// ---------------------------------------------------------------------------
// Phase 1: approx scores via 3-pass bf16 MFMA, 64 queries/wave, register
// double-buffer B prefetch, fmed3 second-best (r6-verbatim compute).
// Epilogue change: always write positive id; flagged q -> worklist push.
// ---------------------------------------------------------------------------
__global__ __launch_bounds__(256) void vq_approx(const float* __restrict__ codes,
                                                 const short8* __restrict__ bh,
                                                 const short8* __restrict__ bl,
                                                 const float* __restrict__ hcsq,
                                                 float* __restrict__ out_ids,
                                                 int* __restrict__ worklist,
                                                 int* __restrict__ counter) {
    const int lane = threadIdx.x & 63;
    const int wv   = threadIdx.x >> 6;
    const int qb   = (blockIdx.x * 4 + wv) * 64;   // 64 queries per wave
    const int c16  = lane & 15;
    const int kg   = lane >> 4;

    // Load + split 4 A-sets (negated query rows), bf16 hi/lo (verified).
    short8 ah[4][2], al[4][2];
    #pragma unroll
    for (int s = 0; s < 4; ++s) {
        const float* xr = codes + (size_t)(qb + s * 16 + c16) * DIM + kg * 8;
        #pragma unroll
        for (int e = 0; e < 8; ++e) {
            float v = -xr[e];
            unsigned short hb = f2bf_rne(v);
            ah[s][0][e] = (short)hb;
            al[s][0][e] = (short)f2bf_rne(v - bf2f(hb));
            float w = -xr[32 + e];
            unsigned short hw = f2bf_rne(w);
            ah[s][1][e] = (short)hw;
            al[s][1][e] = (short)f2bf_rne(w - bf2f(hw));
        }
    }

    float d1[16], d2[16];
    int   tb[16];
    #pragma unroll
    for (int r = 0; r < 16; ++r) { d1[r] = 3.4e38f; d2[r] = 3.4e38f; tb[r] = 0; }

    // Prefetch tile 0 B-fragments.
    short8 pvh0 = bh[0 * 64 + lane];
    short8 pvl0 = bl[0 * 64 + lane];
    short8 pvh1 = bh[1 * 64 + lane];
    short8 pvl1 = bl[1 * 64 + lane];
    float  phc  = hcsq[c16];

    for (int t = 0; t < NTILES; ++t) {
        short8 vh0 = pvh0, vl0 = pvl0, vh1 = pvh1, vl1 = pvl1;
        float  hc  = phc;
        if (t + 1 < NTILES) {          // issue next-tile loads before MFMA
            pvh0 = bh[(t * 2 + 2) * 64 + lane];
            pvl0 = bl[(t * 2 + 2) * 64 + lane];
            pvh1 = bh[(t * 2 + 3) * 64 + lane];
            pvl1 = bl[(t * 2 + 3) * 64 + lane];
            phc  = hcsq[(t + 1) * 16 + c16];
        }
        f32x4 hcv = {hc, hc, hc, hc};
        #pragma unroll
        for (int s = 0; s < 4; ++s) {
            f32x4 acc = hcv;   // score = 0.5*||c||^2 - x.c
            acc = __builtin_amdgcn_mfma_f32_16x16x32_bf16(ah[s][0], vh0, acc, 0, 0, 0);
            acc = __builtin_amdgcn_mfma_f32_16x16x32_bf16(al[s][0], vh0, acc, 0, 0, 0);
            acc = __builtin_amdgcn_mfma_f32_16x16x32_bf16(ah[s][0], vl0, acc, 0, 0, 0);
            acc = __builtin_amdgcn_mfma_f32_16x16x32_bf16(ah[s][1], vh1, acc, 0, 0, 0);
            acc = __builtin_amdgcn_mfma_f32_16x16x32_bf16(al[s][1], vh1, acc, 0, 0, 0);
            acc = __builtin_amdgcn_mfma_f32_16x16x32_bf16(ah[s][1], vl1, acc, 0, 0, 0);
            #pragma unroll
            for (int rr = 0; rr < 4; ++rr) {
                float d = acc[rr];
                int r = s * 4 + rr;
                bool take = d < d1[r];                    // strict: first min wins
                d2[r] = __builtin_amdgcn_fmed3f(d1[r], d2[r], d);  // min(d2,max(d1,d))
                d1[r] = fminf(d1[r], d);
                tb[r] = take ? t : tb[r];
            }
        }
    }

    // Cross-lane argmin within each 16-lane group (verified butterfly).
    #pragma unroll
    for (int r = 0; r < 16; ++r) {
        float dd1 = d1[r], dd2 = d2[r];
        int idv = tb[r] * 16 + c16;
        #pragma unroll
        for (int m = 1; m < 16; m <<= 1) {
            float d_o  = __shfl_xor(dd1, m, 64);
            int   i_o  = __shfl_xor(idv, m, 64);
            float d2_o = __shfl_xor(dd2, m, 64);
            float nd2 = fminf(fminf(dd2, d2_o), fmaxf(dd1, d_o));
            bool take = (d_o < dd1) || (d_o == dd1 && i_o < idv);
            dd1 = take ? d_o : dd1;
            idv = take ? i_o : idv;
            dd2 = nd2;
        }
        if (c16 == 0) {
            int q = qb + (r >> 2) * 16 + kg * 4 + (r & 3);
            out_ids[q] = (float)idv;                     // always positive
            if (dd2 - dd1 < THR) {                       // near-tie -> rescan
                int slot = atomicAdd(counter, 1);
                worklist[slot] = q;
            }
        }
    }
}

// ---------------------------------------------------------------------------
// Fixup: one wave per worklist entry (grid-stride). Exact fp32 rescan,
// bitwise-identical math to the validated round-1 kernel. Rare -> scratch
// and VGPR pressure here cost nothing globally.
// ---------------------------------------------------------------------------
__global__ __launch_bounds__(256) void vq_fixup(const float* __restrict__ codes,
                                                const float* __restrict__ cb,
                                                const float* __restrict__ hcsq,
                                                const int* __restrict__ worklist,
                                                const int* __restrict__ counter,
                                                float* __restrict__ out_ids) {
    const int lane = threadIdx.x & 63;
    const int wid  = blockIdx.x * 4 + (threadIdx.x >> 6);
    const int nw   = gridDim.x * 4;
    const int cnt  = *counter;

    for (int w = wid; w < cnt; w += nw) {
        const int q = worklist[w];
        float x[64];
        const float4* xp = reinterpret_cast<const float4*>(codes + (size_t)q * DIM);
        #pragma unroll
        for (int i = 0; i < 16; ++i) {
            float4 v = xp[i];
            x[4*i+0] = v.x; x[4*i+1] = v.y; x[4*i+2] = v.z; x[4*i+3] = v.w;
        }
        float best = 3.4e38f; int bid = 0;
        for (int jj = 0; jj < 16; ++jj) {
            int k = jj * 64 + lane;
            const float4* cp = reinterpret_cast<const float4*>(cb + (size_t)k * DIM);
            float acc = hcsq[k];
            #pragma unroll
            for (int i = 0; i < 16; ++i) {
                float4 c = cp[i];
                acc = fmaf(-x[4*i+0], c.x, acc);
                acc = fmaf(-x[4*i+1], c.y, acc);
                acc = fmaf(-x[4*i+2], c.z, acc);
                acc = fmaf(-x[4*i+3], c.w, acc);
            }
            if (acc < best) { best = acc; bid = k; }   // strict: lowest k wins
        }
        #pragma unroll
        for (int m = 1; m < 64; m <<= 1) {
            float d_o = __shfl_xor(best, m, 64);
            int   i_o = __shfl_xor(bid, m, 64);
            bool take = (d_o < best) || (d_o == best && i_o < bid);
            best = take ? d_o : best;
            bid  = take ? i_o : bid;
        }
        int id = __shfl(bid, 0, 64);
        if (lane == 0) out_ids[q] = (float)id;
    }
}

// ---------------------------------------------------------------------------
// Gather: scratch-free streaming. Thread handles 8 float4s of out_codes
// (grid-stride, ids batched first for memory-level parallelism).
// ---------------------------------------------------------------------------
__global__ __launch_bounds__(256) void vq_gather(const float* __restrict__ cb,
                                                 const float* __restrict__ out_ids,
                                                 float4* __restrict__ out_codes4) {
    const int base = blockIdx.x * 256 + threadIdx.x;
    const int STRIDE = 2048 * 256;                 // total threads
    const float4* cb4 = reinterpret_cast<const float4*>(cb);

    float fids[8];
    #pragma unroll
    for (int u = 0; u < 8; ++u)
        fids[u] = out_ids[(base + u * STRIDE) >> 4];

    #pragma unroll
    for (int u = 0; u < 8; ++u) {
        int i = base + u * STRIDE;
        int id = (int)fids[u];
        out_codes4[i] = cb4[id * 16 + (i & 15)];
    }
}

// ---------------------------------------------------------------------------
extern "C" void kernel_launch(void* const* d_in, const int* in_sizes, int n_in,
                              void* d_out, int out_size, void* d_ws, size_t ws_size,
                              hipStream_t stream) {
    const float* codes = (const float*)d_in[0];
    const float* cb    = (const float*)d_in[1];
    float* out         = (float*)d_out;

    float* out_codes = out;
    float* out_ids   = out + (size_t)M_TOTAL * DIM;

    // ws: [0,4K) hcsq | [4K,132K) bh | [132K,260K) bl | [264K) counter |
    //     [268K, 268K+1M) worklist
    float*  hcsq     = (float*)d_ws;
    short8* bh       = (short8*)((char*)d_ws + 4096);
    short8* bl       = (short8*)((char*)d_ws + 4096 + 128 * 1024);
    int*    counter  = (int*)((char*)d_ws + 264 * 1024);
    int*    worklist = (int*)((char*)d_ws + 268 * 1024);

    csq_kernel<<<NUM_NT, 64, 0, stream>>>(cb, hcsq, counter);
    cb_convert<<<32, 256, 0, stream>>>(cb, bh, bl);
    vq_approx<<<M_TOTAL / 256, 256, 0, stream>>>(codes, bh, bl, hcsq,
                                                 out_ids, worklist, counter);
    vq_fixup<<<256, 256, 0, stream>>>(codes, cb, hcsq, worklist, counter, out_ids);
    vq_gather<<<2048, 256, 0, stream>>>(cb, out_ids, (float4*)out_codes);
}

// Round 11
// 216.717 us; speedup vs baseline: 3.1264x; 1.0283x over previous
//
#include <hip/hip_runtime.h>

// VQ nearest-neighbor: codes (64,4096,64) fp32, codebook (1024,64) fp32.
// Outputs flat in d_out: quant_codes [M*64] f32, then quant_id [M] (as f32).
//
// Round 10 = round 7 VERBATIM (verified pass, 222.8us) with ONE change:
// vq_approx gets __launch_bounds__(256, 2) -> up to 256 unified regs/lane,
// so the ~150-reg live set (A-frags + d1/d2/tb + B dbuf) stays in
// architectural VGPRs instead of AGPRs (r7: VGPR_Count=88 => ~60 values in
// AGPRs => v_accvgpr_read/write on every tracking op => 4.6x VALU inflation).
// Embedded-id tracking is permanently abandoned (failed 4/4: r3,r4,r8,r9).

#define NUM_NT 1024
#define DIM 64
#define M_TOTAL (64 * 4096)
#define NTILES 64
#define THR 2.5e-3f            // raw-gap threshold, verified rounds 2/5/6/7

typedef __attribute__((ext_vector_type(8))) short short8;   // 8 bf16
typedef __attribute__((ext_vector_type(4))) float f32x4;

static __device__ __forceinline__ unsigned short f2bf_rne(float f) {
    unsigned u = __builtin_bit_cast(unsigned, f);
    u += 0x7FFFu + ((u >> 16) & 1u);          // round-to-nearest-even
    return (unsigned short)(u >> 16);
}
static __device__ __forceinline__ float bf2f(unsigned short h) {
    unsigned u = ((unsigned)h) << 16;
    return __builtin_bit_cast(float, u);
}

// ---------------------------------------------------------------------------
// Phase 0a: hcsq[k] = 0.5*||c_k||^2; block 0 zeroes the worklist counter.
// (r7-verbatim)
// ---------------------------------------------------------------------------
__global__ __launch_bounds__(64) void csq_kernel(const float* __restrict__ cb,
                                                 float* __restrict__ hcsq,
                                                 int* __restrict__ counter) {
    int k = blockIdx.x, d = threadIdx.x;
    if (k == 0 && d == 0) *counter = 0;
    float v = cb[k * DIM + d];
    float s = v * v;
    #pragma unroll
    for (int off = 32; off > 0; off >>= 1) s += __shfl_down(s, off);
    if (d == 0) hcsq[k] = 0.5f * s;
}

// ---------------------------------------------------------------------------
// Phase 0b: codebook -> bf16 hi/lo fragments in MFMA B-layout. (r7-verbatim)
// ---------------------------------------------------------------------------
__global__ __launch_bounds__(256) void cb_convert(const float* __restrict__ cb,
                                                  short8* __restrict__ bh,
                                                  short8* __restrict__ bl) {
    int gtid = blockIdx.x * 256 + threadIdx.x;   // 8192 = 128 frags x 64 lanes
    int f = gtid >> 6;
    int lane = gtid & 63;
    int t = f >> 1, kk = f & 1;
    int n = t * 16 + (lane & 15);
    int k0 = kk * 32 + 8 * (lane >> 4);
    const float* p = cb + n * DIM + k0;
    short8 h, l;
    #pragma unroll
    for (int e = 0; e < 8; ++e) {
        float v = p[e];
        unsigned short hb = f2bf_rne(v);
        h[e] = (short)hb;
        l[e] = (short)f2bf_rne(v - bf2f(hb));
    }
    bh[f * 64 + lane] = h;
    bl[f * 64 + lane] = l;
}

// ---------------------------------------------------------------------------
// Phase 1: approx scores via 3-pass bf16 MFMA, 64 queries/wave, register
// double-buffer B prefetch, fmed3 second-best. Tracking/reduction/marker
// r7-VERBATIM. ONLY change: __launch_bounds__(256, 2).
// ---------------------------------------------------------------------------
__global__ __launch_bounds__(256, 2) void vq_approx(const float* __restrict__ codes,
                                                    const short8* __restrict__ bh,
                                                    const short8* __restrict__ bl,
                                                    const float* __restrict__ hcsq,
                                                    float* __restrict__ out_ids,
                                                    int* __restrict__ worklist,
                                                    int* __restrict__ counter) {
    const int lane = threadIdx.x & 63;
    const int wv   = threadIdx.x >> 6;
    const int qb   = (blockIdx.x * 4 + wv) * 64;   // 64 queries per wave
    const int c16  = lane & 15;
    const int kg   = lane >> 4;

    // Load + split 4 A-sets (negated query rows), bf16 hi/lo (verified).
    short8 ah[4][2], al[4][2];
    #pragma unroll
    for (int s = 0; s < 4; ++s) {
        const float* xr = codes + (size_t)(qb + s * 16 + c16) * DIM + kg * 8;
        #pragma unroll
        for (int e = 0; e < 8; ++e) {
            float v = -xr[e];
            unsigned short hb = f2bf_rne(v);
            ah[s][0][e] = (short)hb;
            al[s][0][e] = (short)f2bf_rne(v - bf2f(hb));
            float w = -xr[32 + e];
            unsigned short hw = f2bf_rne(w);
            ah[s][1][e] = (short)hw;
            al[s][1][e] = (short)f2bf_rne(w - bf2f(hw));
        }
    }

    float d1[16], d2[16];
    int   tb[16];
    #pragma unroll
    for (int r = 0; r < 16; ++r) { d1[r] = 3.4e38f; d2[r] = 3.4e38f; tb[r] = 0; }

    // Prefetch tile 0 B-fragments.
    short8 pvh0 = bh[0 * 64 + lane];
    short8 pvl0 = bl[0 * 64 + lane];
    short8 pvh1 = bh[1 * 64 + lane];
    short8 pvl1 = bl[1 * 64 + lane];
    float  phc  = hcsq[c16];

    for (int t = 0; t < NTILES; ++t) {
        short8 vh0 = pvh0, vl0 = pvl0, vh1 = pvh1, vl1 = pvl1;
        float  hc  = phc;
        if (t + 1 < NTILES) {            // issue next-tile loads before MFMA
            pvh0 = bh[(t * 2 + 2) * 64 + lane];
            pvl0 = bl[(t * 2 + 2) * 64 + lane];
            pvh1 = bh[(t * 2 + 3) * 64 + lane];
            pvl1 = bl[(t * 2 + 3) * 64 + lane];
            phc  = hcsq[(t + 1) * 16 + c16];
        }
        f32x4 hcv = {hc, hc, hc, hc};
        #pragma unroll
        for (int s = 0; s < 4; ++s) {
            f32x4 acc = hcv;   // score = 0.5*||c||^2 - x.c
            acc = __builtin_amdgcn_mfma_f32_16x16x32_bf16(ah[s][0], vh0, acc, 0, 0, 0);
            acc = __builtin_amdgcn_mfma_f32_16x16x32_bf16(al[s][0], vh0, acc, 0, 0, 0);
            acc = __builtin_amdgcn_mfma_f32_16x16x32_bf16(ah[s][0], vl0, acc, 0, 0, 0);
            acc = __builtin_amdgcn_mfma_f32_16x16x32_bf16(ah[s][1], vh1, acc, 0, 0, 0);
            acc = __builtin_amdgcn_mfma_f32_16x16x32_bf16(al[s][1], vh1, acc, 0, 0, 0);
            acc = __builtin_amdgcn_mfma_f32_16x16x32_bf16(ah[s][1], vl1, acc, 0, 0, 0);
            #pragma unroll
            for (int rr = 0; rr < 4; ++rr) {
                float d = acc[rr];
                int r = s * 4 + rr;
                bool take = d < d1[r];                    // strict: first min wins
                d2[r] = __builtin_amdgcn_fmed3f(d1[r], d2[r], d);  // min(d2,max(d1,d))
                d1[r] = fminf(d1[r], d);
                tb[r] = take ? t : tb[r];
            }
        }
    }

    // Cross-lane argmin within each 16-lane group (verified butterfly).
    #pragma unroll
    for (int r = 0; r < 16; ++r) {
        float dd1 = d1[r], dd2 = d2[r];
        int idv = tb[r] * 16 + c16;
        #pragma unroll
        for (int m = 1; m < 16; m <<= 1) {
            float d_o  = __shfl_xor(dd1, m, 64);
            int   i_o  = __shfl_xor(idv, m, 64);
            float d2_o = __shfl_xor(dd2, m, 64);
            float nd2 = fminf(fminf(dd2, d2_o), fmaxf(dd1, d_o));
            bool take = (d_o < dd1) || (d_o == dd1 && i_o < idv);
            dd1 = take ? d_o : dd1;
            idv = take ? i_o : idv;
            dd2 = nd2;
        }
        if (c16 == 0) {
            int q = qb + (r >> 2) * 16 + kg * 4 + (r & 3);
            out_ids[q] = (float)idv;                     // always positive
            if (dd2 - dd1 < THR) {                       // near-tie -> rescan
                int slot = atomicAdd(counter, 1);
                worklist[slot] = q;
            }
        }
    }
}

// ---------------------------------------------------------------------------
// Fixup: one wave per worklist entry (grid-stride). Exact fp32 rescan,
// bitwise-identical math to the validated round-1 kernel. (r7-verbatim)
// ---------------------------------------------------------------------------
__global__ __launch_bounds__(256) void vq_fixup(const float* __restrict__ codes,
                                                const float* __restrict__ cb,
                                                const float* __restrict__ hcsq,
                                                const int* __restrict__ worklist,
                                                const int* __restrict__ counter,
                                                float* __restrict__ out_ids) {
    const int lane = threadIdx.x & 63;
    const int wid  = blockIdx.x * 4 + (threadIdx.x >> 6);
    const int nw   = gridDim.x * 4;
    const int cnt  = *counter;

    for (int w = wid; w < cnt; w += nw) {
        const int q = worklist[w];
        float x[64];
        const float4* xp = reinterpret_cast<const float4*>(codes + (size_t)q * DIM);
        #pragma unroll
        for (int i = 0; i < 16; ++i) {
            float4 v = xp[i];
            x[4*i+0] = v.x; x[4*i+1] = v.y; x[4*i+2] = v.z; x[4*i+3] = v.w;
        }
        float best = 3.4e38f; int bid = 0;
        for (int jj = 0; jj < 16; ++jj) {
            int k = jj * 64 + lane;
            const float4* cp = reinterpret_cast<const float4*>(cb + (size_t)k * DIM);
            float acc = hcsq[k];
            #pragma unroll
            for (int i = 0; i < 16; ++i) {
                float4 c = cp[i];
                acc = fmaf(-x[4*i+0], c.x, acc);
                acc = fmaf(-x[4*i+1], c.y, acc);
                acc = fmaf(-x[4*i+2], c.z, acc);
                acc = fmaf(-x[4*i+3], c.w, acc);
            }
            if (acc < best) { best = acc; bid = k; }   // strict: lowest k wins
        }
        #pragma unroll
        for (int m = 1; m < 64; m <<= 1) {
            float d_o = __shfl_xor(best, m, 64);
            int   i_o = __shfl_xor(bid, m, 64);
            bool take = (d_o < best) || (d_o == best && i_o < bid);
            best = take ? d_o : best;
            bid  = take ? i_o : bid;
        }
        int id = __shfl(bid, 0, 64);
        if (lane == 0) out_ids[q] = (float)id;
    }
}

// ---------------------------------------------------------------------------
// Gather: scratch-free streaming gather/store of codebook rows. (r7-verbatim)
// ---------------------------------------------------------------------------
__global__ __launch_bounds__(256) void vq_gather(const float* __restrict__ cb,
                                                 const float* __restrict__ out_ids,
                                                 float4* __restrict__ out_codes4) {
    const int base = blockIdx.x * 256 + threadIdx.x;
    const int STRIDE = 2048 * 256;                 // total threads
    const float4* cb4 = reinterpret_cast<const float4*>(cb);

    float fids[8];
    #pragma unroll
    for (int u = 0; u < 8; ++u)
        fids[u] = out_ids[(base + u * STRIDE) >> 4];

    #pragma unroll
    for (int u = 0; u < 8; ++u) {
        int i = base + u * STRIDE;
        int id = (int)fids[u];
        out_codes4[i] = cb4[id * 16 + (i & 15)];
    }
}

// ---------------------------------------------------------------------------
extern "C" void kernel_launch(void* const* d_in, const int* in_sizes, int n_in,
                              void* d_out, int out_size, void* d_ws, size_t ws_size,
                              hipStream_t stream) {
    const float* codes = (const float*)d_in[0];
    const float* cb    = (const float*)d_in[1];
    float* out         = (float*)d_out;

    float* out_codes = out;
    float* out_ids   = out + (size_t)M_TOTAL * DIM;

    // ws: [0,4K) hcsq | [4K,132K) bh | [132K,260K) bl | [264K) counter |
    //     [268K, 268K+1M) worklist
    float*  hcsq     = (float*)d_ws;
    short8* bh       = (short8*)((char*)d_ws + 4096);
    short8* bl       = (short8*)((char*)d_ws + 4096 + 128 * 1024);
    int*    counter  = (int*)((char*)d_ws + 264 * 1024);
    int*    worklist = (int*)((char*)d_ws + 268 * 1024);

    csq_kernel<<<NUM_NT, 64, 0, stream>>>(cb, hcsq, counter);
    cb_convert<<<32, 256, 0, stream>>>(cb, bh, bl);
    vq_approx<<<M_TOTAL / 256, 256, 0, stream>>>(codes, bh, bl, hcsq,
                                                 out_ids, worklist, counter);
    vq_fixup<<<512, 256, 0, stream>>>(codes, cb, hcsq, worklist, counter, out_ids);
    vq_gather<<<2048, 256, 0, stream>>>(cb, out_ids, (float4*)out_codes);
}

// Round 12
// 204.343 us; speedup vs baseline: 3.3157x; 1.0606x over previous
//
#include <hip/hip_runtime.h>

// VQ nearest-neighbor: codes (64,4096,64) fp32, codebook (1024,64) fp32.
// Outputs flat in d_out: quant_codes [M*64] f32, then quant_id [M] (as f32).
//
// Round 11 = round 10 (verified pass, 216.7us) with ONE change: vq_fixup ->
// vq_fixup8: 8 flagged queries per wave share one codebook pass (x vectors
// LDS-broadcast, codeword rows VGPR-resident, 8 independent FMA chains).
// Per-(q,k) FMA order bitwise-identical to validated r1 math.
// approx / csq / convert / gather are r10-VERBATIM.

#define NUM_NT 1024
#define DIM 64
#define M_TOTAL (64 * 4096)
#define NTILES 64
#define THR 2.5e-3f            // raw-gap threshold, verified rounds 2/5/6/7/10

typedef __attribute__((ext_vector_type(8))) short short8;   // 8 bf16
typedef __attribute__((ext_vector_type(4))) float f32x4;

static __device__ __forceinline__ unsigned short f2bf_rne(float f) {
    unsigned u = __builtin_bit_cast(unsigned, f);
    u += 0x7FFFu + ((u >> 16) & 1u);          // round-to-nearest-even
    return (unsigned short)(u >> 16);
}
static __device__ __forceinline__ float bf2f(unsigned short h) {
    unsigned u = ((unsigned)h) << 16;
    return __builtin_bit_cast(float, u);
}

// ---------------------------------------------------------------------------
// Phase 0a: hcsq[k] = 0.5*||c_k||^2; block 0 zeroes the worklist counter.
// (r10-verbatim)
// ---------------------------------------------------------------------------
__global__ __launch_bounds__(64) void csq_kernel(const float* __restrict__ cb,
                                                 float* __restrict__ hcsq,
                                                 int* __restrict__ counter) {
    int k = blockIdx.x, d = threadIdx.x;
    if (k == 0 && d == 0) *counter = 0;
    float v = cb[k * DIM + d];
    float s = v * v;
    #pragma unroll
    for (int off = 32; off > 0; off >>= 1) s += __shfl_down(s, off);
    if (d == 0) hcsq[k] = 0.5f * s;
}

// ---------------------------------------------------------------------------
// Phase 0b: codebook -> bf16 hi/lo fragments in MFMA B-layout. (r10-verbatim)
// ---------------------------------------------------------------------------
__global__ __launch_bounds__(256) void cb_convert(const float* __restrict__ cb,
                                                  short8* __restrict__ bh,
                                                  short8* __restrict__ bl) {
    int gtid = blockIdx.x * 256 + threadIdx.x;   // 8192 = 128 frags x 64 lanes
    int f = gtid >> 6;
    int lane = gtid & 63;
    int t = f >> 1, kk = f & 1;
    int n = t * 16 + (lane & 15);
    int k0 = kk * 32 + 8 * (lane >> 4);
    const float* p = cb + n * DIM + k0;
    short8 h, l;
    #pragma unroll
    for (int e = 0; e < 8; ++e) {
        float v = p[e];
        unsigned short hb = f2bf_rne(v);
        h[e] = (short)hb;
        l[e] = (short)f2bf_rne(v - bf2f(hb));
    }
    bh[f * 64 + lane] = h;
    bl[f * 64 + lane] = l;
}

// ---------------------------------------------------------------------------
// Phase 1: approx scores via 3-pass bf16 MFMA, 64 queries/wave, register
// double-buffer B prefetch, fmed3 second-best. (r10-verbatim)
// ---------------------------------------------------------------------------
__global__ __launch_bounds__(256, 2) void vq_approx(const float* __restrict__ codes,
                                                    const short8* __restrict__ bh,
                                                    const short8* __restrict__ bl,
                                                    const float* __restrict__ hcsq,
                                                    float* __restrict__ out_ids,
                                                    int* __restrict__ worklist,
                                                    int* __restrict__ counter) {
    const int lane = threadIdx.x & 63;
    const int wv   = threadIdx.x >> 6;
    const int qb   = (blockIdx.x * 4 + wv) * 64;   // 64 queries per wave
    const int c16  = lane & 15;
    const int kg   = lane >> 4;

    short8 ah[4][2], al[4][2];
    #pragma unroll
    for (int s = 0; s < 4; ++s) {
        const float* xr = codes + (size_t)(qb + s * 16 + c16) * DIM + kg * 8;
        #pragma unroll
        for (int e = 0; e < 8; ++e) {
            float v = -xr[e];
            unsigned short hb = f2bf_rne(v);
            ah[s][0][e] = (short)hb;
            al[s][0][e] = (short)f2bf_rne(v - bf2f(hb));
            float w = -xr[32 + e];
            unsigned short hw = f2bf_rne(w);
            ah[s][1][e] = (short)hw;
            al[s][1][e] = (short)f2bf_rne(w - bf2f(hw));
        }
    }

    float d1[16], d2[16];
    int   tb[16];
    #pragma unroll
    for (int r = 0; r < 16; ++r) { d1[r] = 3.4e38f; d2[r] = 3.4e38f; tb[r] = 0; }

    short8 pvh0 = bh[0 * 64 + lane];
    short8 pvl0 = bl[0 * 64 + lane];
    short8 pvh1 = bh[1 * 64 + lane];
    short8 pvl1 = bl[1 * 64 + lane];
    float  phc  = hcsq[c16];

    for (int t = 0; t < NTILES; ++t) {
        short8 vh0 = pvh0, vl0 = pvl0, vh1 = pvh1, vl1 = pvl1;
        float  hc  = phc;
        if (t + 1 < NTILES) {            // issue next-tile loads before MFMA
            pvh0 = bh[(t * 2 + 2) * 64 + lane];
            pvl0 = bl[(t * 2 + 2) * 64 + lane];
            pvh1 = bh[(t * 2 + 3) * 64 + lane];
            pvl1 = bl[(t * 2 + 3) * 64 + lane];
            phc  = hcsq[(t + 1) * 16 + c16];
        }
        f32x4 hcv = {hc, hc, hc, hc};
        #pragma unroll
        for (int s = 0; s < 4; ++s) {
            f32x4 acc = hcv;   // score = 0.5*||c||^2 - x.c
            acc = __builtin_amdgcn_mfma_f32_16x16x32_bf16(ah[s][0], vh0, acc, 0, 0, 0);
            acc = __builtin_amdgcn_mfma_f32_16x16x32_bf16(al[s][0], vh0, acc, 0, 0, 0);
            acc = __builtin_amdgcn_mfma_f32_16x16x32_bf16(ah[s][0], vl0, acc, 0, 0, 0);
            acc = __builtin_amdgcn_mfma_f32_16x16x32_bf16(ah[s][1], vh1, acc, 0, 0, 0);
            acc = __builtin_amdgcn_mfma_f32_16x16x32_bf16(al[s][1], vh1, acc, 0, 0, 0);
            acc = __builtin_amdgcn_mfma_f32_16x16x32_bf16(ah[s][1], vl1, acc, 0, 0, 0);
            #pragma unroll
            for (int rr = 0; rr < 4; ++rr) {
                float d = acc[rr];
                int r = s * 4 + rr;
                bool take = d < d1[r];                    // strict: first min wins
                d2[r] = __builtin_amdgcn_fmed3f(d1[r], d2[r], d);  // min(d2,max(d1,d))
                d1[r] = fminf(d1[r], d);
                tb[r] = take ? t : tb[r];
            }
        }
    }

    #pragma unroll
    for (int r = 0; r < 16; ++r) {
        float dd1 = d1[r], dd2 = d2[r];
        int idv = tb[r] * 16 + c16;
        #pragma unroll
        for (int m = 1; m < 16; m <<= 1) {
            float d_o  = __shfl_xor(dd1, m, 64);
            int   i_o  = __shfl_xor(idv, m, 64);
            float d2_o = __shfl_xor(dd2, m, 64);
            float nd2 = fminf(fminf(dd2, d2_o), fmaxf(dd1, d_o));
            bool take = (d_o < dd1) || (d_o == dd1 && i_o < idv);
            dd1 = take ? d_o : dd1;
            idv = take ? i_o : idv;
            dd2 = nd2;
        }
        if (c16 == 0) {
            int q = qb + (r >> 2) * 16 + kg * 4 + (r & 3);
            out_ids[q] = (float)idv;
            if (dd2 - dd1 < THR) {                       // near-tie -> rescan
                int slot = atomicAdd(counter, 1);
                worklist[slot] = q;
            }
        }
    }
}

// ---------------------------------------------------------------------------
// Fixup8: each wave resolves 8 flagged queries per codebook pass.
//   - 8 x-vectors staged in LDS (broadcast reads)
//   - lane owns rows k = jj*64+lane, row resident in VGPRs, 8 indep chains
//   - per-(q,k) FMA order bitwise-identical to r1: acc=hcsq[k]; fmaf(-x,c,acc)
//   - 64-lane lex (score,id) butterfly r1-verbatim; strict lowest-k wins
// ---------------------------------------------------------------------------
__global__ __launch_bounds__(256) void vq_fixup8(const float* __restrict__ codes,
                                                 const float* __restrict__ cb,
                                                 const float* __restrict__ hcsq,
                                                 const int* __restrict__ worklist,
                                                 const int* __restrict__ counter,
                                                 float* __restrict__ out_ids) {
    __shared__ float xs[4][8][64];            // per-wave 2KB staging
    const int lane = threadIdx.x & 63;
    const int wv   = threadIdx.x >> 6;
    const int wid  = blockIdx.x * 4 + wv;
    const int nw   = gridDim.x * 4;
    const int cnt  = *counter;
    const int ngrp = (cnt + 7) >> 3;

    for (int g = wid; g < ngrp; g += nw) {
        const int qbase = g * 8;
        const int nq = min(8, cnt - qbase);

        // Stage 8 query vectors (pad with first entry; benign duplicate work).
        int qw[8];
        #pragma unroll
        for (int j = 0; j < 8; ++j) {
            qw[j] = worklist[qbase + (j < nq ? j : 0)];
        }
        // ensure prior iteration's reads finished before overwriting xs
        __builtin_amdgcn_sched_barrier(0);
        asm volatile("s_waitcnt lgkmcnt(0)" ::: "memory");
        #pragma unroll
        for (int j = 0; j < 8; ++j) {
            xs[wv][j][lane] = codes[(size_t)qw[j] * DIM + lane];
        }
        // wave-synchronous: make writes visible to all lanes' reads
        __builtin_amdgcn_sched_barrier(0);
        asm volatile("s_waitcnt lgkmcnt(0) vmcnt(0)" ::: "memory");
        __builtin_amdgcn_sched_barrier(0);

        float best[8]; int bid[8];
        #pragma unroll
        for (int j = 0; j < 8; ++j) { best[j] = 3.4e38f; bid[j] = 0; }

        for (int jj = 0; jj < 16; ++jj) {
            const int k = jj * 64 + lane;
            const float4* cp = reinterpret_cast<const float4*>(cb + (size_t)k * DIM);
            float4 c[16];
            #pragma unroll
            for (int i = 0; i < 16; ++i) c[i] = cp[i];
            const float hck = hcsq[k];
            #pragma unroll
            for (int q = 0; q < 8; ++q) {
                float acc = hck;
                #pragma unroll
                for (int i = 0; i < 16; ++i) {
                    const float4* xv = reinterpret_cast<const float4*>(&xs[wv][q][i * 4]);
                    float4 x = *xv;
                    acc = fmaf(-x.x, c[i].x, acc);
                    acc = fmaf(-x.y, c[i].y, acc);
                    acc = fmaf(-x.z, c[i].z, acc);
                    acc = fmaf(-x.w, c[i].w, acc);
                }
                if (acc < best[q]) { best[q] = acc; bid[q] = k; }  // lowest k wins
            }
        }

        #pragma unroll
        for (int q = 0; q < 8; ++q) {
            float b = best[q]; int i1 = bid[q];
            #pragma unroll
            for (int m = 1; m < 64; m <<= 1) {
                float d_o = __shfl_xor(b, m, 64);
                int   i_o = __shfl_xor(i1, m, 64);
                bool take = (d_o < b) || (d_o == b && i_o < i1);
                b  = take ? d_o : b;
                i1 = take ? i_o : i1;
            }
            int id = __shfl(i1, 0, 64);
            if (lane == 0 && q < nq) out_ids[qw[q]] = (float)id;
        }
    }
}

// ---------------------------------------------------------------------------
// Gather: scratch-free streaming gather/store of codebook rows. (r10-verbatim)
// ---------------------------------------------------------------------------
__global__ __launch_bounds__(256) void vq_gather(const float* __restrict__ cb,
                                                 const float* __restrict__ out_ids,
                                                 float4* __restrict__ out_codes4) {
    const int base = blockIdx.x * 256 + threadIdx.x;
    const int STRIDE = 2048 * 256;                 // total threads
    const float4* cb4 = reinterpret_cast<const float4*>(cb);

    float fids[8];
    #pragma unroll
    for (int u = 0; u < 8; ++u)
        fids[u] = out_ids[(base + u * STRIDE) >> 4];

    #pragma unroll
    for (int u = 0; u < 8; ++u) {
        int i = base + u * STRIDE;
        int id = (int)fids[u];
        out_codes4[i] = cb4[id * 16 + (i & 15)];
    }
}

// ---------------------------------------------------------------------------
extern "C" void kernel_launch(void* const* d_in, const int* in_sizes, int n_in,
                              void* d_out, int out_size, void* d_ws, size_t ws_size,
                              hipStream_t stream) {
    const float* codes = (const float*)d_in[0];
    const float* cb    = (const float*)d_in[1];
    float* out         = (float*)d_out;

    float* out_codes = out;
    float* out_ids   = out + (size_t)M_TOTAL * DIM;

    // ws: [0,4K) hcsq | [4K,132K) bh | [132K,260K) bl | [264K) counter |
    //     [268K, 268K+1M) worklist
    float*  hcsq     = (float*)d_ws;
    short8* bh       = (short8*)((char*)d_ws + 4096);
    short8* bl       = (short8*)((char*)d_ws + 4096 + 128 * 1024);
    int*    counter  = (int*)((char*)d_ws + 264 * 1024);
    int*    worklist = (int*)((char*)d_ws + 268 * 1024);

    csq_kernel<<<NUM_NT, 64, 0, stream>>>(cb, hcsq, counter);
    cb_convert<<<32, 256, 0, stream>>>(cb, bh, bl);
    vq_approx<<<M_TOTAL / 256, 256, 0, stream>>>(codes, bh, bl, hcsq,
                                                 out_ids, worklist, counter);
    vq_fixup8<<<256, 256, 0, stream>>>(codes, cb, hcsq, worklist, counter, out_ids);
    vq_gather<<<2048, 256, 0, stream>>>(cb, out_ids, (float4*)out_codes);
}

// Round 13
// 160.598 us; speedup vs baseline: 4.2189x; 1.2724x over previous
//
#include <hip/hip_runtime.h>

// VQ nearest-neighbor: codes (64,4096,64) fp32, codebook (1024,64) fp32.
// Outputs flat in d_out: quant_codes [M*64] f32, then quant_id [M] (as f32).
//
// Round 13 = round 12 with the spill-crippled fixup8 REVERTED to the
// verified 1-query/wave fixup (r10-verbatim), THR tightened 2.5e-3 -> 1e-3
// (5x margin over the ~2e-4 worst-case 3-pass error; cuts flagged count
// ~2.5x => fixup is cnt-linear), and gather re-gridded for more MLP.
// approx / csq / convert are r12-VERBATIM.

#define NUM_NT 1024
#define DIM 64
#define M_TOTAL (64 * 4096)
#define NTILES 64
#define THR 1.0e-3f            // >= 5x the ~2e-4 worst-case 3-pass gap error

typedef __attribute__((ext_vector_type(8))) short short8;   // 8 bf16
typedef __attribute__((ext_vector_type(4))) float f32x4;

static __device__ __forceinline__ unsigned short f2bf_rne(float f) {
    unsigned u = __builtin_bit_cast(unsigned, f);
    u += 0x7FFFu + ((u >> 16) & 1u);          // round-to-nearest-even
    return (unsigned short)(u >> 16);
}
static __device__ __forceinline__ float bf2f(unsigned short h) {
    unsigned u = ((unsigned)h) << 16;
    return __builtin_bit_cast(float, u);
}

// ---------------------------------------------------------------------------
// Phase 0a: hcsq[k] = 0.5*||c_k||^2; block 0 zeroes the worklist counter.
// (r12-verbatim)
// ---------------------------------------------------------------------------
__global__ __launch_bounds__(64) void csq_kernel(const float* __restrict__ cb,
                                                 float* __restrict__ hcsq,
                                                 int* __restrict__ counter) {
    int k = blockIdx.x, d = threadIdx.x;
    if (k == 0 && d == 0) *counter = 0;
    float v = cb[k * DIM + d];
    float s = v * v;
    #pragma unroll
    for (int off = 32; off > 0; off >>= 1) s += __shfl_down(s, off);
    if (d == 0) hcsq[k] = 0.5f * s;
}

// ---------------------------------------------------------------------------
// Phase 0b: codebook -> bf16 hi/lo fragments in MFMA B-layout. (r12-verbatim)
// ---------------------------------------------------------------------------
__global__ __launch_bounds__(256) void cb_convert(const float* __restrict__ cb,
                                                  short8* __restrict__ bh,
                                                  short8* __restrict__ bl) {
    int gtid = blockIdx.x * 256 + threadIdx.x;   // 8192 = 128 frags x 64 lanes
    int f = gtid >> 6;
    int lane = gtid & 63;
    int t = f >> 1, kk = f & 1;
    int n = t * 16 + (lane & 15);
    int k0 = kk * 32 + 8 * (lane >> 4);
    const float* p = cb + n * DIM + k0;
    short8 h, l;
    #pragma unroll
    for (int e = 0; e < 8; ++e) {
        float v = p[e];
        unsigned short hb = f2bf_rne(v);
        h[e] = (short)hb;
        l[e] = (short)f2bf_rne(v - bf2f(hb));
    }
    bh[f * 64 + lane] = h;
    bl[f * 64 + lane] = l;
}

// ---------------------------------------------------------------------------
// Phase 1: approx scores via 3-pass bf16 MFMA, 64 queries/wave, register
// double-buffer B prefetch, fmed3 second-best. (r12-verbatim)
// ---------------------------------------------------------------------------
__global__ __launch_bounds__(256, 2) void vq_approx(const float* __restrict__ codes,
                                                    const short8* __restrict__ bh,
                                                    const short8* __restrict__ bl,
                                                    const float* __restrict__ hcsq,
                                                    float* __restrict__ out_ids,
                                                    int* __restrict__ worklist,
                                                    int* __restrict__ counter) {
    const int lane = threadIdx.x & 63;
    const int wv   = threadIdx.x >> 6;
    const int qb   = (blockIdx.x * 4 + wv) * 64;   // 64 queries per wave
    const int c16  = lane & 15;
    const int kg   = lane >> 4;

    short8 ah[4][2], al[4][2];
    #pragma unroll
    for (int s = 0; s < 4; ++s) {
        const float* xr = codes + (size_t)(qb + s * 16 + c16) * DIM + kg * 8;
        #pragma unroll
        for (int e = 0; e < 8; ++e) {
            float v = -xr[e];
            unsigned short hb = f2bf_rne(v);
            ah[s][0][e] = (short)hb;
            al[s][0][e] = (short)f2bf_rne(v - bf2f(hb));
            float w = -xr[32 + e];
            unsigned short hw = f2bf_rne(w);
            ah[s][1][e] = (short)hw;
            al[s][1][e] = (short)f2bf_rne(w - bf2f(hw));
        }
    }

    float d1[16], d2[16];
    int   tb[16];
    #pragma unroll
    for (int r = 0; r < 16; ++r) { d1[r] = 3.4e38f; d2[r] = 3.4e38f; tb[r] = 0; }

    short8 pvh0 = bh[0 * 64 + lane];
    short8 pvl0 = bl[0 * 64 + lane];
    short8 pvh1 = bh[1 * 64 + lane];
    short8 pvl1 = bl[1 * 64 + lane];
    float  phc  = hcsq[c16];

    for (int t = 0; t < NTILES; ++t) {
        short8 vh0 = pvh0, vl0 = pvl0, vh1 = pvh1, vl1 = pvl1;
        float  hc  = phc;
        if (t + 1 < NTILES) {            // issue next-tile loads before MFMA
            pvh0 = bh[(t * 2 + 2) * 64 + lane];
            pvl0 = bl[(t * 2 + 2) * 64 + lane];
            pvh1 = bh[(t * 2 + 3) * 64 + lane];
            pvl1 = bl[(t * 2 + 3) * 64 + lane];
            phc  = hcsq[(t + 1) * 16 + c16];
        }
        f32x4 hcv = {hc, hc, hc, hc};
        #pragma unroll
        for (int s = 0; s < 4; ++s) {
            f32x4 acc = hcv;   // score = 0.5*||c||^2 - x.c
            acc = __builtin_amdgcn_mfma_f32_16x16x32_bf16(ah[s][0], vh0, acc, 0, 0, 0);
            acc = __builtin_amdgcn_mfma_f32_16x16x32_bf16(al[s][0], vh0, acc, 0, 0, 0);
            acc = __builtin_amdgcn_mfma_f32_16x16x32_bf16(ah[s][0], vl0, acc, 0, 0, 0);
            acc = __builtin_amdgcn_mfma_f32_16x16x32_bf16(ah[s][1], vh1, acc, 0, 0, 0);
            acc = __builtin_amdgcn_mfma_f32_16x16x32_bf16(al[s][1], vh1, acc, 0, 0, 0);
            acc = __builtin_amdgcn_mfma_f32_16x16x32_bf16(ah[s][1], vl1, acc, 0, 0, 0);
            #pragma unroll
            for (int rr = 0; rr < 4; ++rr) {
                float d = acc[rr];
                int r = s * 4 + rr;
                bool take = d < d1[r];                    // strict: first min wins
                d2[r] = __builtin_amdgcn_fmed3f(d1[r], d2[r], d);  // min(d2,max(d1,d))
                d1[r] = fminf(d1[r], d);
                tb[r] = take ? t : tb[r];
            }
        }
    }

    #pragma unroll
    for (int r = 0; r < 16; ++r) {
        float dd1 = d1[r], dd2 = d2[r];
        int idv = tb[r] * 16 + c16;
        #pragma unroll
        for (int m = 1; m < 16; m <<= 1) {
            float d_o  = __shfl_xor(dd1, m, 64);
            int   i_o  = __shfl_xor(idv, m, 64);
            float d2_o = __shfl_xor(dd2, m, 64);
            float nd2 = fminf(fminf(dd2, d2_o), fmaxf(dd1, d_o));
            bool take = (d_o < dd1) || (d_o == dd1 && i_o < idv);
            dd1 = take ? d_o : dd1;
            idv = take ? i_o : idv;
            dd2 = nd2;
        }
        if (c16 == 0) {
            int q = qb + (r >> 2) * 16 + kg * 4 + (r & 3);
            out_ids[q] = (float)idv;
            if (dd2 - dd1 < THR) {                       // near-tie -> rescan
                int slot = atomicAdd(counter, 1);
                worklist[slot] = q;
            }
        }
    }
}

// ---------------------------------------------------------------------------
// Fixup: one wave per worklist entry (grid-stride). Exact fp32 rescan,
// bitwise-identical math to the validated round-1 kernel. (r10-verbatim)
// ---------------------------------------------------------------------------
__global__ __launch_bounds__(256) void vq_fixup(const float* __restrict__ codes,
                                                const float* __restrict__ cb,
                                                const float* __restrict__ hcsq,
                                                const int* __restrict__ worklist,
                                                const int* __restrict__ counter,
                                                float* __restrict__ out_ids) {
    const int lane = threadIdx.x & 63;
    const int wid  = blockIdx.x * 4 + (threadIdx.x >> 6);
    const int nw   = gridDim.x * 4;
    const int cnt  = *counter;

    for (int w = wid; w < cnt; w += nw) {
        const int q = worklist[w];
        float x[64];
        const float4* xp = reinterpret_cast<const float4*>(codes + (size_t)q * DIM);
        #pragma unroll
        for (int i = 0; i < 16; ++i) {
            float4 v = xp[i];
            x[4*i+0] = v.x; x[4*i+1] = v.y; x[4*i+2] = v.z; x[4*i+3] = v.w;
        }
        float best = 3.4e38f; int bid = 0;
        for (int jj = 0; jj < 16; ++jj) {
            int k = jj * 64 + lane;
            const float4* cp = reinterpret_cast<const float4*>(cb + (size_t)k * DIM);
            float acc = hcsq[k];
            #pragma unroll
            for (int i = 0; i < 16; ++i) {
                float4 c = cp[i];
                acc = fmaf(-x[4*i+0], c.x, acc);
                acc = fmaf(-x[4*i+1], c.y, acc);
                acc = fmaf(-x[4*i+2], c.z, acc);
                acc = fmaf(-x[4*i+3], c.w, acc);
            }
            if (acc < best) { best = acc; bid = k; }   // strict: lowest k wins
        }
        #pragma unroll
        for (int m = 1; m < 64; m <<= 1) {
            float d_o = __shfl_xor(best, m, 64);
            int   i_o = __shfl_xor(bid, m, 64);
            bool take = (d_o < best) || (d_o == best && i_o < bid);
            best = take ? d_o : best;
            bid  = take ? i_o : bid;
        }
        int id = __shfl(bid, 0, 64);
        if (lane == 0) out_ids[q] = (float)id;
    }
}

// ---------------------------------------------------------------------------
// Gather: scratch-free streaming gather/store of codebook rows.
// 4096 blocks x 4 float4/thread (ids batched first for MLP).
// ---------------------------------------------------------------------------
__global__ __launch_bounds__(256) void vq_gather(const float* __restrict__ cb,
                                                 const float* __restrict__ out_ids,
                                                 float4* __restrict__ out_codes4) {
    const int base = blockIdx.x * 256 + threadIdx.x;
    const int STRIDE = 4096 * 256;                 // total threads
    const float4* cb4 = reinterpret_cast<const float4*>(cb);

    float fids[4];
    #pragma unroll
    for (int u = 0; u < 4; ++u)
        fids[u] = out_ids[(base + u * STRIDE) >> 4];

    #pragma unroll
    for (int u = 0; u < 4; ++u) {
        int i = base + u * STRIDE;
        int id = (int)fids[u];
        out_codes4[i] = cb4[id * 16 + (i & 15)];
    }
}

// ---------------------------------------------------------------------------
extern "C" void kernel_launch(void* const* d_in, const int* in_sizes, int n_in,
                              void* d_out, int out_size, void* d_ws, size_t ws_size,
                              hipStream_t stream) {
    const float* codes = (const float*)d_in[0];
    const float* cb    = (const float*)d_in[1];
    float* out         = (float*)d_out;

    float* out_codes = out;
    float* out_ids   = out + (size_t)M_TOTAL * DIM;

    // ws: [0,4K) hcsq | [4K,132K) bh | [132K,260K) bl | [264K) counter |
    //     [268K, 268K+1M) worklist
    float*  hcsq     = (float*)d_ws;
    short8* bh       = (short8*)((char*)d_ws + 4096);
    short8* bl       = (short8*)((char*)d_ws + 4096 + 128 * 1024);
    int*    counter  = (int*)((char*)d_ws + 264 * 1024);
    int*    worklist = (int*)((char*)d_ws + 268 * 1024);

    csq_kernel<<<NUM_NT, 64, 0, stream>>>(cb, hcsq, counter);
    cb_convert<<<32, 256, 0, stream>>>(cb, bh, bl);
    vq_approx<<<M_TOTAL / 256, 256, 0, stream>>>(codes, bh, bl, hcsq,
                                                 out_ids, worklist, counter);
    vq_fixup<<<512, 256, 0, stream>>>(codes, cb, hcsq, worklist, counter, out_ids);
    vq_gather<<<4096, 256, 0, stream>>>(cb, out_ids, (float4*)out_codes);
}